// Round 5
// baseline (229.573 us; speedup 1.0000x reference)
//
#include <hip/hip_runtime.h>
#include <stdint.h>

#define B_TOT 16384
#define IN_DIM 128
#define H1 256
#define H2 128
#define NC 10

// LDS: W2T rows 0..255 (= [256][128] f32) + one 128-float zero row.
#define ZBYTE (H1 * H2 * 4)                 // 131072: byte offset of zero row
#define LDS_FLOATS (H1 * H2 + H2)           // 32896 floats = 131584 B

typedef float v2f __attribute__((ext_vector_type(2)));

// ---------------------------------------------------------------------------
// Kernel A: cur1[b][n] = sum_k x[b][k]*W1[n][k] + b1[n]
// 32 rows/block, 256 threads = 256 neurons, acc[32]/thread.
// x-tile LDS reads are wave-broadcast (all lanes same address) -> cheap.
// ---------------------------------------------------------------------------
__global__ __launch_bounds__(256) void gemm1_kernel(
    const float* __restrict__ x, const float* __restrict__ W1,
    const float* __restrict__ b1, float* __restrict__ cur1) {
  __shared__ float xs[32 * 128];  // 16 KB
  const int tid = threadIdx.x;
  const long row0 = (long)blockIdx.x * 32;

  const float4* xt = (const float4*)(x + row0 * IN_DIM);  // 1024 float4
  float4* xs4 = (float4*)xs;
#pragma unroll
  for (int i = 0; i < 4; ++i) xs4[tid + i * 256] = xt[tid + i * 256];
  __syncthreads();

  const int n = tid;
  float acc[32];
#pragma unroll
  for (int r = 0; r < 32; ++r) acc[r] = 0.f;

  const float* wrow = W1 + n * IN_DIM;
  for (int k0 = 0; k0 < IN_DIM; k0 += 4) {
    const float4 wv = *(const float4*)(wrow + k0);
#pragma unroll
    for (int r = 0; r < 32; ++r) {
      const float4 xv = *(const float4*)(xs + r * IN_DIM + k0);
      acc[r] = fmaf(wv.x, xv.x, acc[r]);
      acc[r] = fmaf(wv.y, xv.y, acc[r]);
      acc[r] = fmaf(wv.z, xv.z, acc[r]);
      acc[r] = fmaf(wv.w, xv.w, acc[r]);
    }
  }
  const float bias = b1[n];
#pragma unroll
  for (int r = 0; r < 32; ++r)
    cur1[(row0 + r) * H1 + n] = acc[r] + bias;
}

// ---------------------------------------------------------------------------
// Kernel A2: W2 (128x256 -> 256x128) and Wo (10x128 -> 128x10) transposed
// into workspace, plus a 16-float zero pad after WoT (dummy-read target).
// ---------------------------------------------------------------------------
__global__ __launch_bounds__(1024) void transpose_kernel(
    const float* __restrict__ W2, const float* __restrict__ Wo,
    float* __restrict__ W2T, float* __restrict__ WoT) {
  const int idx = blockIdx.x * 1024 + threadIdx.x;
  if (idx < H2 * H1) {
    const int o = idx >> 8;
    const int j = idx & 255;
    W2T[j * H2 + o] = W2[idx];
  } else if (idx < H2 * H1 + NC * H2) {
    const int k = idx - H2 * H1;
    const int o = k >> 7;
    const int j = k & 127;
    WoT[j * NC + o] = Wo[k];
  } else if (idx < H2 * H1 + NC * H2 + 16) {
    WoT[idx - H2 * H1] = 0.f;  // zero pad at WoT[1280..1295]
  }
}

// ---------------------------------------------------------------------------
// Branchless spike-offset extraction (wave-uniform masks -> pure SALU:
// s_ff1 + s_cselect + s_and). Returns a BYTE offset; empty mask -> zoff
// (points at a zero row, so the consuming add is +0.0f = exact).
// ---------------------------------------------------------------------------
__device__ __forceinline__ int ext_off(unsigned long long& m, int zoff) {
  const unsigned long long t = m ? m : 1ULL;          // avoid ctz(0) UB
  const int j = (int)__builtin_ctzll(t);
  const int off = m ? (j << 9) : zoff;                // j * 512 B (row stride)
  m = m & (m - 1);                                    // 0 stays 0
  return off;
}

__device__ __forceinline__ int ext_ooff(unsigned long long& m, int oo) {
  const unsigned long long t = m ? m : 1ULL;
  const int j = (int)__builtin_ctzll(t);
  const int off = m ? ((2 * j + oo) * (NC * 4)) : (H2 * NC * 4);  // dummy=5120
  m = m & (m - 1);
  return off;
}

// ---------------------------------------------------------------------------
// Kernel B: fused 20-step recurrent SNN. 256 persistent blocks (1/CU),
// 16 waves/block, 4 rows/wave. W2T in LDS (131 KB + zero row); WoT read
// from GLOBAL (5 KB, L1-resident) to keep the LDS pipe for W2 rows.
// Sparse sums: branchless always-load 4-deep pipeline, scalar-selected
// byte offsets, zero-row dummies trailing each group -> summation is
// bit-identical to the verified round-2 order.
// ---------------------------------------------------------------------------
__global__ __launch_bounds__(1024) void snn_kernel(
    const float* __restrict__ cur1,
    const float* __restrict__ W2Tg, const float* __restrict__ WoTg,
    const float* __restrict__ x, const float* __restrict__ W1,
    const float* __restrict__ b1,
    const float* __restrict__ b2, const float* __restrict__ bo,
    const int* __restrict__ nsp, float* __restrict__ out) {
  extern __shared__ float lds[];
  float* w2t = lds;  // [256][128] + zero row

  const int tid = threadIdx.x;
  {
    float4* dst = (float4*)w2t;
    const float4* src = (const float4*)W2Tg;
#pragma unroll
    for (int i = 0; i < 8; ++i) dst[tid + i * 1024] = src[tid + i * 1024];
    if (tid < 32)
      ((float4*)(w2t + H1 * H2))[tid] = make_float4(0.f, 0.f, 0.f, 0.f);
  }
  __syncthreads();

  const int w = tid >> 6;
  const int l = tid & 63;
  const int lo = (l < NC) ? l : 0;
  const float bb0 = b2[2 * l];
  const float bb1 = b2[2 * l + 1];
  const float bol = bo[lo];
  const char* w2l = (const char*)(w2t + 2 * l);     // lane's pair base (LDS)
  const char* wol = (const char*)(WoTg + lo);       // lane's out base (global)
  const int nsteps = *nsp;

  for (int r = 0; r < 4; ++r) {
    const long b = (long)blockIdx.x * 64 + w * 4 + r;

    float c[4];
    if (cur1 != nullptr) {
#pragma unroll
      for (int i = 0; i < 4; ++i) c[i] = cur1[b * H1 + i * 64 + l];
    } else {
      const float* xr = x + b * IN_DIM;
#pragma unroll
      for (int i = 0; i < 4; ++i) {
        const int n = i * 64 + l;
        const float* wr = W1 + n * IN_DIM;
        float a = 0.f;
        for (int k = 0; k < IN_DIM; k += 4) {
          const float4 wv = *(const float4*)(wr + k);
          const float4 xv = *(const float4*)(xr + k);
          a = fmaf(wv.x, xv.x, a);
          a = fmaf(wv.y, xv.y, a);
          a = fmaf(wv.z, xv.z, a);
          a = fmaf(wv.w, xv.w, a);
        }
        c[i] = a + b1[n];
      }
    }

    float m1[4] = {0.f, 0.f, 0.f, 0.f};
    float sp1[4] = {0.f, 0.f, 0.f, 0.f};
    float m2a = 0.f, m2b = 0.f, sp2a = 0.f, sp2b = 0.f;
    float mo = 0.f, spo = 0.f, cnt = 0.f;
    const v2f zz = {0.f, 0.f};

    for (int t = 0; t < nsteps; ++t) {
      // ---- layer 1 LIF ----
      unsigned long long mk[4];
#pragma unroll
      for (int i = 0; i < 4; ++i) {
        m1[i] = fmaf(0.5f, m1[i], c[i]) - sp1[i];
        const bool s = m1[i] > 1.0f;
        mk[i] = __ballot(s);
        sp1[i] = s ? 1.0f : 0.0f;
      }

      // ---- cur2 = s1 @ W2^T (+ b2): branchless 4-deep pipelined sparse
      //      sum; dummies hit the zero row (scalar relative offset) ----
      v2f acc = zz;
#pragma unroll
      for (int i = 0; i < 4; ++i) {
        unsigned long long m = mk[i];
        const char* base = w2l + i * (64 * H2 * 4);
        const int zr = ZBYTE - i * (64 * H2 * 4);  // zero row, group-relative
        const int o0 = ext_off(m, zr);
        const int o1 = ext_off(m, zr);
        const int o2 = ext_off(m, zr);
        const int o3 = ext_off(m, zr);
        v2f v0 = *(const v2f*)(base + o0);
        v2f v1 = *(const v2f*)(base + o1);
        v2f v2v = *(const v2f*)(base + o2);
        v2f v3 = *(const v2f*)(base + o3);
        while (m) {
          const int p0 = ext_off(m, zr);
          const int p1 = ext_off(m, zr);
          const int p2 = ext_off(m, zr);
          const int p3 = ext_off(m, zr);
          const v2f u0 = *(const v2f*)(base + p0);
          const v2f u1 = *(const v2f*)(base + p1);
          const v2f u2 = *(const v2f*)(base + p2);
          const v2f u3 = *(const v2f*)(base + p3);
          acc += v0;
          acc += v1;
          acc += v2v;
          acc += v3;
          v0 = u0; v1 = u1; v2v = u2; v3 = u3;
        }
        acc += v0;
        acc += v1;
        acc += v2v;
        acc += v3;
      }
      const float a0 = acc.x + bb0;
      const float a1 = acc.y + bb1;

      // ---- layer 2 LIF ----
      m2a = fmaf(0.5f, m2a, a0) - sp2a;
      m2b = fmaf(0.5f, m2b, a1) - sp2b;
      const bool sa = m2a > 1.0f;
      const bool sb = m2b > 1.0f;
      unsigned long long mA = __ballot(sa);
      unsigned long long mB = __ballot(sb);
      sp2a = sa ? 1.0f : 0.0f;
      sp2b = sb ? 1.0f : 0.0f;

      // ---- output layer: 8 always-issued GLOBAL loads (L1-resident WoT),
      //      scalar offsets, zero-pad dummies; adds evens then odds ----
      const int a0o = ext_ooff(mA, 0);
      const int a1o = ext_ooff(mA, 0);
      const int a2o = ext_ooff(mA, 0);
      const int a3o = ext_ooff(mA, 0);
      const int b0o = ext_ooff(mB, 1);
      const int b1o = ext_ooff(mB, 1);
      const int b2o = ext_ooff(mB, 1);
      const int b3o = ext_ooff(mB, 1);
      const float va0 = *(const float*)(wol + a0o);
      const float va1 = *(const float*)(wol + a1o);
      const float va2 = *(const float*)(wol + a2o);
      const float va3 = *(const float*)(wol + a3o);
      const float vb0 = *(const float*)(wol + b0o);
      const float vb1 = *(const float*)(wol + b1o);
      const float vb2 = *(const float*)(wol + b2o);
      const float vb3 = *(const float*)(wol + b3o);

      float co = 0.f;
      co += va0; co += va1; co += va2; co += va3;
      while (mA) {  // rare tail (>4 even spikes)
        const int j = __builtin_ctzll(mA);
        mA &= mA - 1;
        co += *(const float*)(wol + (2 * j) * (NC * 4));
      }
      co += vb0; co += vb1; co += vb2; co += vb3;
      while (mB) {  // rare tail (>4 odd spikes)
        const int j = __builtin_ctzll(mB);
        mB &= mB - 1;
        co += *(const float*)(wol + (2 * j + 1) * (NC * 4));
      }
      co += bol;

      // ---- output LIF + spike count ----
      mo = fmaf(0.5f, mo, co) - spo;
      const bool so = mo > 1.0f;
      spo = so ? 1.0f : 0.0f;
      cnt += spo;
    }

    if (l < NC) out[b * NC + l] = cnt;
  }
}

// ---------------------------------------------------------------------------
extern "C" void kernel_launch(void* const* d_in, const int* in_sizes, int n_in,
                              void* d_out, int out_size, void* d_ws,
                              size_t ws_size, hipStream_t stream) {
  const float* x  = (const float*)d_in[0];
  const float* W1 = (const float*)d_in[1];
  const float* b1 = (const float*)d_in[2];
  const float* W2 = (const float*)d_in[3];
  const float* b2 = (const float*)d_in[4];
  const float* Wo = (const float*)d_in[5];
  const float* bo = (const float*)d_in[6];
  const int* nsp  = (const int*)d_in[7];
  float* outp = (float*)d_out;

  // ws layout: W2T (32768 f) | WoT+zeropad (1296 f) | cur1 (16384*256 f)
  float* W2Tg = (float*)d_ws;
  float* WoTg = W2Tg + H1 * H2;
  float* cur1p = WoTg + (NC * H2 + 16);
  const size_t small_f = (size_t)(H1 * H2 + NC * H2 + 16);
  const size_t need = (small_f + (size_t)B_TOT * H1) * sizeof(float);

  transpose_kernel<<<(H2 * H1 + NC * H2 + 16 + 1023) / 1024, 1024, 0,
                     stream>>>(W2, Wo, W2Tg, WoTg);

  float* cur1 = nullptr;
  if (ws_size >= need) {
    cur1 = cur1p;
    gemm1_kernel<<<B_TOT / 32, 256, 0, stream>>>(x, W1, b1, cur1);
  }

  const size_t ldsB = (size_t)LDS_FLOATS * sizeof(float);  // 131584 B
  hipFuncSetAttribute((const void*)snn_kernel,
                      hipFuncAttributeMaxDynamicSharedMemorySize, (int)ldsB);
  snn_kernel<<<256, 1024, ldsB, stream>>>(cur1, W2Tg, WoTg, x, W1, b1, b2, bo,
                                          nsp, outp);
}

// Round 6
// 180.999 us; speedup vs baseline: 1.2684x; 1.2684x over previous
//
#include <hip/hip_runtime.h>
#include <stdint.h>

#define B_TOT 16384
#define IN_DIM 128
#define H1 256
#define H2 128
#define NC 10

// LDS layout: W2T rows 0..255 = data, row 256 = zeros (odd-tail dummy).
//             WoT rows 0..127 = data, row 128 = zeros (unused this round).
#define W2T_ROWS 257
#define WOT_ROWS 129
#define LDS_FLOATS (W2T_ROWS * H2 + WOT_ROWS * NC)

typedef float v2f __attribute__((ext_vector_type(2)));

// ---------------------------------------------------------------------------
// Kernel A: cur1[b][n] = sum_k x[b][k]*W1[n][k] + b1[n]   (r2 version)
// ---------------------------------------------------------------------------
__global__ __launch_bounds__(256) void gemm1_kernel(
    const float* __restrict__ x, const float* __restrict__ W1,
    const float* __restrict__ b1, float* __restrict__ cur1) {
  __shared__ float xs[16 * 128];
  const int tid = threadIdx.x;
  const long row0 = (long)blockIdx.x * 16;

  const float4* xt = (const float4*)(x + row0 * IN_DIM);
  float4* xs4 = (float4*)xs;
  xs4[tid] = xt[tid];
  xs4[tid + 256] = xt[tid + 256];
  __syncthreads();

  const int n = tid;
  float acc[16];
#pragma unroll
  for (int r = 0; r < 16; ++r) acc[r] = 0.f;

  const float* wrow = W1 + n * IN_DIM;
  for (int k0 = 0; k0 < IN_DIM; k0 += 4) {
    const float4 wv = *(const float4*)(wrow + k0);
#pragma unroll
    for (int r = 0; r < 16; ++r) {
      const float4 xv = *(const float4*)(xs + r * IN_DIM + k0);
      acc[r] = fmaf(wv.x, xv.x, acc[r]);
      acc[r] = fmaf(wv.y, xv.y, acc[r]);
      acc[r] = fmaf(wv.z, xv.z, acc[r]);
      acc[r] = fmaf(wv.w, xv.w, acc[r]);
    }
  }
  const float bias = b1[n];
#pragma unroll
  for (int r = 0; r < 16; ++r)
    cur1[(row0 + r) * H1 + n] = acc[r] + bias;
}

// ---------------------------------------------------------------------------
// Kernel A2: global transpose of W2 / Wo into workspace.   (r2 version)
// ---------------------------------------------------------------------------
__global__ __launch_bounds__(1024) void transpose_kernel(
    const float* __restrict__ W2, const float* __restrict__ Wo,
    float* __restrict__ W2T, float* __restrict__ WoT) {
  const int idx = blockIdx.x * 1024 + threadIdx.x;
  if (idx < H2 * H1) {
    const int o = idx >> 8;
    const int j = idx & 255;
    W2T[j * H2 + o] = W2[idx];
  } else {
    const int k = idx - H2 * H1;
    if (k < NC * H2) {
      const int o = k >> 7;
      const int j = k & 127;
      WoT[j * NC + o] = Wo[k];
    }
  }
}

// ---------------------------------------------------------------------------
// Next-spike ROW extraction on a wave-uniform mask (pure SALU: s_ff1 +
// s_cselect + s_and). Empty mask -> jz (zero row relative to group base),
// so the consuming add is +0.0f = exact.
// ---------------------------------------------------------------------------
__device__ __forceinline__ int ext_row(unsigned long long& m, int jz) {
  const unsigned long long t = m ? m : 1ULL;  // avoid ctz(0) UB
  const int j = (int)__builtin_ctzll(t);
  const int row = m ? j : jz;
  m = m & (m - 1);  // 0 stays 0
  return row;
}

// ---------------------------------------------------------------------------
// Kernel B: fused 20-step recurrent SNN. 256 persistent blocks (1/CU),
// 16 waves/block, 4 rows/wave. Identical to the 127us round-2 kernel
// EXCEPT the W2 group loop: 2-deep software pipeline with scalar trip
// count (nb = ceil(popc/2)), single basic block, at most ONE zero-row
// dummy per group (odd tail, appended last -> +0.0f, bit-exact order).
// ---------------------------------------------------------------------------
__global__ __launch_bounds__(1024) void snn_kernel(
    const float* __restrict__ cur1,
    const float* __restrict__ W2Tg, const float* __restrict__ WoTg,
    const float* __restrict__ W2, const float* __restrict__ Wo,
    const float* __restrict__ x, const float* __restrict__ W1,
    const float* __restrict__ b1,
    const float* __restrict__ b2, const float* __restrict__ bo,
    const int* __restrict__ nsp, float* __restrict__ out) {
  extern __shared__ float lds[];
  float* w2t = lds;                       // [257][128]
  float* wot = lds + W2T_ROWS * H2;       // [129][10]

  const int tid = threadIdx.x;
  if (W2Tg != nullptr) {
    float4* dst = (float4*)w2t;
    const float4* src = (const float4*)W2Tg;
#pragma unroll
    for (int i = 0; i < 8; ++i) dst[tid + i * 1024] = src[tid + i * 1024];
    if (tid < 320) ((float4*)wot)[tid] = ((const float4*)WoTg)[tid];
  } else {
    for (int idx = tid; idx < H2 * H1; idx += 1024) {
      const int o = idx >> 8;
      const int j = idx & 255;
      w2t[j * H2 + o] = W2[idx];
    }
    for (int idx = tid; idx < NC * H2; idx += 1024) {
      const int o = idx >> 7;
      const int j = idx & 127;
      wot[j * NC + o] = Wo[idx];
    }
  }
  // zero rows (dummy targets)
  if (tid < 32)
    ((float4*)(w2t + 256 * H2))[tid] = make_float4(0.f, 0.f, 0.f, 0.f);
  if (tid < NC) wot[128 * NC + tid] = 0.f;
  __syncthreads();

  const int w = tid >> 6;
  const int l = tid & 63;
  const int lo = (l < NC) ? l : 0;
  const float bb0 = b2[2 * l];
  const float bb1 = b2[2 * l + 1];
  const float bol = bo[lo];
  const float* w2l = w2t + 2 * l;  // lane's output pair within a row
  const int nsteps = *nsp;
  const v2f zz = {0.f, 0.f};

  for (int r = 0; r < 4; ++r) {
    const long b = (long)blockIdx.x * 64 + w * 4 + r;

    float c[4];
    if (cur1 != nullptr) {
#pragma unroll
      for (int i = 0; i < 4; ++i) c[i] = cur1[b * H1 + i * 64 + l];
    } else {
      const float* xr = x + b * IN_DIM;
#pragma unroll
      for (int i = 0; i < 4; ++i) {
        const int n = i * 64 + l;
        const float* wr = W1 + n * IN_DIM;
        float a = 0.f;
        for (int k = 0; k < IN_DIM; k += 4) {
          const float4 wv = *(const float4*)(wr + k);
          const float4 xv = *(const float4*)(xr + k);
          a = fmaf(wv.x, xv.x, a);
          a = fmaf(wv.y, xv.y, a);
          a = fmaf(wv.z, xv.z, a);
          a = fmaf(wv.w, xv.w, a);
        }
        c[i] = a + b1[n];
      }
    }

    float m1[4] = {0.f, 0.f, 0.f, 0.f};
    float sp1[4] = {0.f, 0.f, 0.f, 0.f};
    float m2a = 0.f, m2b = 0.f, sp2a = 0.f, sp2b = 0.f;
    float mo = 0.f, spo = 0.f, cnt = 0.f;

    for (int t = 0; t < nsteps; ++t) {
      // ---- layer 1 LIF ----
      unsigned long long mk[4];
#pragma unroll
      for (int i = 0; i < 4; ++i) {
        m1[i] = fmaf(0.5f, m1[i], c[i]) - sp1[i];
        const bool s = m1[i] > 1.0f;
        mk[i] = __ballot(s);
        sp1[i] = s ? 1.0f : 0.0f;
      }

      // ---- cur2 = s1 @ W2^T (+ b2): 2-deep pipelined sparse sum ----
      v2f acc = zz;
#pragma unroll
      for (int i = 0; i < 4; ++i) {
        unsigned long long m = mk[i];
        if (m == 0ULL) continue;
        const float* base = w2l + (i * 64) * H2;
        const int jz = 256 - i * 64;  // zero row, relative to group base
        const int nb = (__popcll(m) + 1) >> 1;

        int j0 = ext_row(m, jz);
        int j1 = ext_row(m, jz);
        v2f v0 = *(const v2f*)(base + j0 * H2);
        v2f v1 = *(const v2f*)(base + j1 * H2);
        for (int p = 1; p < nb; ++p) {
          const int q0 = ext_row(m, jz);
          const int q1 = ext_row(m, jz);
          const v2f u0 = *(const v2f*)(base + q0 * H2);
          const v2f u1 = *(const v2f*)(base + q1 * H2);
          acc += v0;
          acc += v1;
          v0 = u0;
          v1 = u1;
        }
        acc += v0;
        acc += v1;
      }
      const float a0 = acc.x + bb0;
      const float a1 = acc.y + bb1;

      // ---- layer 2 LIF ----
      m2a = fmaf(0.5f, m2a, a0) - sp2a;
      m2b = fmaf(0.5f, m2b, a1) - sp2b;
      const bool sa = m2a > 1.0f;
      const bool sb = m2b > 1.0f;
      unsigned long long mA = __ballot(sa);
      unsigned long long mB = __ballot(sb);
      sp2a = sa ? 1.0f : 0.0f;
      sp2b = sb ? 1.0f : 0.0f;

      // ---- output layer: r2-exact serial loops (LDS wot) ----
      float co = 0.f;
      while (mA) {
        const int j = __builtin_ctzll(mA);
        mA &= mA - 1;
        co += wot[(2 * j) * NC + lo];
      }
      while (mB) {
        const int j = __builtin_ctzll(mB);
        mB &= mB - 1;
        co += wot[(2 * j + 1) * NC + lo];
      }
      co += bol;

      // ---- output LIF + spike count ----
      mo = fmaf(0.5f, mo, co) - spo;
      const bool so = mo > 1.0f;
      spo = so ? 1.0f : 0.0f;
      cnt += spo;
    }

    if (l < NC) out[b * NC + l] = cnt;
  }
}

// ---------------------------------------------------------------------------
extern "C" void kernel_launch(void* const* d_in, const int* in_sizes, int n_in,
                              void* d_out, int out_size, void* d_ws,
                              size_t ws_size, hipStream_t stream) {
  const float* x  = (const float*)d_in[0];
  const float* W1 = (const float*)d_in[1];
  const float* b1 = (const float*)d_in[2];
  const float* W2 = (const float*)d_in[3];
  const float* b2 = (const float*)d_in[4];
  const float* Wo = (const float*)d_in[5];
  const float* bo = (const float*)d_in[6];
  const int* nsp  = (const int*)d_in[7];
  float* outp = (float*)d_out;

  const size_t cur1_bytes = (size_t)B_TOT * H1 * sizeof(float);
  const size_t w2t_bytes  = (size_t)H1 * H2 * sizeof(float);
  const size_t wot_bytes  = (size_t)H2 * NC * sizeof(float);

  float* cur1 = nullptr;
  float* W2Tg = nullptr;
  float* WoTg = nullptr;

  if (ws_size >= cur1_bytes) {
    cur1 = (float*)d_ws;
    gemm1_kernel<<<B_TOT / 16, 256, 0, stream>>>(x, W1, b1, cur1);
  }
  if (ws_size >= cur1_bytes + w2t_bytes + wot_bytes) {
    W2Tg = (float*)((char*)d_ws + cur1_bytes);
    WoTg = W2Tg + H1 * H2;
    transpose_kernel<<<(H2 * H1 + NC * H2 + 1023) / 1024, 1024, 0, stream>>>(
        W2, Wo, W2Tg, WoTg);
  }

  const size_t ldsB = (size_t)LDS_FLOATS * sizeof(float);  // ~133.6 KB
  hipFuncSetAttribute((const void*)snn_kernel,
                      hipFuncAttributeMaxDynamicSharedMemorySize, (int)ldsB);
  snn_kernel<<<256, 1024, ldsB, stream>>>(cur1, W2Tg, WoTg, W2, Wo, x, W1, b1,
                                          b2, bo, nsp, outp);
}

// Round 7
// 121.096 us; speedup vs baseline: 1.8958x; 1.4947x over previous
//
#include <hip/hip_runtime.h>
#include <stdint.h>

#define B_TOT 16384
#define IN_DIM 128
#define H1 256
#define H2 128
#define NC 10

// LDS byte layout: W2T [256][128] f32 | WoT [128][10] f32 | 16x 1KB scratch
#define W2T_BYTES (H1 * H2 * 4)            // 131072
#define WOT_OFF   W2T_BYTES
#define WOT_BYTES (H2 * NC * 4)            // 5120
#define SCR_OFF   (WOT_OFF + WOT_BYTES)    // 136192
#define LDS_BYTES (SCR_OFF + 16 * 1024)    // 152576

typedef float v2f __attribute__((ext_vector_type(2)));

// ---------------------------------------------------------------------------
// Kernel A: cur1[b][n] = sum_k x[b][k]*W1[n][k] + b1[n]   (r2 version)
// ---------------------------------------------------------------------------
__global__ __launch_bounds__(256) void gemm1_kernel(
    const float* __restrict__ x, const float* __restrict__ W1,
    const float* __restrict__ b1, float* __restrict__ cur1) {
  __shared__ float xs[16 * 128];
  const int tid = threadIdx.x;
  const long row0 = (long)blockIdx.x * 16;

  const float4* xt = (const float4*)(x + row0 * IN_DIM);
  float4* xs4 = (float4*)xs;
  xs4[tid] = xt[tid];
  xs4[tid + 256] = xt[tid + 256];
  __syncthreads();

  const int n = tid;
  float acc[16];
#pragma unroll
  for (int r = 0; r < 16; ++r) acc[r] = 0.f;

  const float* wrow = W1 + n * IN_DIM;
  for (int k0 = 0; k0 < IN_DIM; k0 += 4) {
    const float4 wv = *(const float4*)(wrow + k0);
#pragma unroll
    for (int r = 0; r < 16; ++r) {
      const float4 xv = *(const float4*)(xs + r * IN_DIM + k0);
      acc[r] = fmaf(wv.x, xv.x, acc[r]);
      acc[r] = fmaf(wv.y, xv.y, acc[r]);
      acc[r] = fmaf(wv.z, xv.z, acc[r]);
      acc[r] = fmaf(wv.w, xv.w, acc[r]);
    }
  }
  const float bias = b1[n];
#pragma unroll
  for (int r = 0; r < 16; ++r)
    cur1[(row0 + r) * H1 + n] = acc[r] + bias;
}

// ---------------------------------------------------------------------------
// Kernel A2: global transpose of W2 / Wo into workspace.   (r2 version)
// ---------------------------------------------------------------------------
__global__ __launch_bounds__(1024) void transpose_kernel(
    const float* __restrict__ W2, const float* __restrict__ Wo,
    float* __restrict__ W2T, float* __restrict__ WoT) {
  const int idx = blockIdx.x * 1024 + threadIdx.x;
  if (idx < H2 * H1) {
    const int o = idx >> 8;
    const int j = idx & 255;
    W2T[j * H2 + o] = W2[idx];
  } else {
    const int k = idx - H2 * H1;
    if (k < NC * H2) {
      const int o = k >> 7;
      const int j = k & 127;
      WoT[j * NC + o] = Wo[k];
    }
  }
}

__device__ __forceinline__ int mbcnt64(unsigned long long m) {
  return (int)__builtin_amdgcn_mbcnt_hi(
      (unsigned)(m >> 32), __builtin_amdgcn_mbcnt_lo((unsigned)m, 0u));
}

// ---------------------------------------------------------------------------
// Kernel B: fused 20-step recurrent SNN. 256 persistent blocks (1/CU),
// 16 waves/block, 4 rows/wave.
// Per row-step the spiking rows' BYTE OFFSETS are compacted (rank =
// cumulative popcount + mbcnt) into a per-wave LDS index list, then
// consumed in exact-size batches of 8/4/2/1: idx reads are broadcast
// ds_read_b128, row loads cluster back-to-back, adds are ordered ->
// bit-identical to the verified r2 summation (j ascending, bias last;
// output layer evens-then-odds).
// ---------------------------------------------------------------------------
__global__ __launch_bounds__(1024) void snn_kernel(
    const float* __restrict__ cur1,
    const float* __restrict__ W2Tg, const float* __restrict__ WoTg,
    const float* __restrict__ W2, const float* __restrict__ Wo,
    const float* __restrict__ x, const float* __restrict__ W1,
    const float* __restrict__ b1,
    const float* __restrict__ b2, const float* __restrict__ bo,
    const int* __restrict__ nsp, float* __restrict__ out) {
  extern __shared__ float lds[];
  float* w2t = lds;                      // [256][128]
  float* wot = lds + H1 * H2;            // [128][10]

  const int tid = threadIdx.x;
  if (W2Tg != nullptr) {
    float4* dst = (float4*)w2t;
    const float4* src = (const float4*)W2Tg;
#pragma unroll
    for (int i = 0; i < 8; ++i) dst[tid + i * 1024] = src[tid + i * 1024];
    if (tid < 320) ((float4*)wot)[tid] = ((const float4*)WoTg)[tid];
  } else {
    for (int idx = tid; idx < H2 * H1; idx += 1024) {
      const int o = idx >> 8;
      const int j = idx & 255;
      w2t[j * H2 + o] = W2[idx];
    }
    for (int idx = tid; idx < NC * H2; idx += 1024) {
      const int o = idx >> 7;
      const int j = idx & 127;
      wot[j * NC + o] = Wo[idx];
    }
  }
  __syncthreads();

  const int w = tid >> 6;
  const int l = tid & 63;
  const int lo = (l < NC) ? l : 0;
  const float bb0 = b2[2 * l];
  const float bb1 = b2[2 * l + 1];
  const float bol = bo[lo];
  const int nsteps = *nsp;

  int* scr = (int*)((char*)lds + SCR_OFF) + w * 256;  // per-wave index list
  const char* w2b = (const char*)lds + 8 * l;         // + row*512
  const char* wob = (const char*)lds + WOT_OFF + 4 * lo;  // + row*40

  // per-lane constant byte offsets of the rows this lane may contribute
  const int wr0 = l << 9;
  const int wr1 = (64 + l) << 9;
  const int wr2 = (128 + l) << 9;
  const int wr3 = (192 + l) << 9;
  const int or0 = 80 * l;        // even output row 2l
  const int or1 = 80 * l + 40;   // odd output row 2l+1

#define MAIN_B8()                                     \
  {                                                   \
    const int4 ia = *(const int4*)(scr + k);          \
    const int4 ib = *(const int4*)(scr + k + 4);      \
    const v2f p0 = *(const v2f*)(w2b + ia.x);         \
    const v2f p1 = *(const v2f*)(w2b + ia.y);         \
    const v2f p2 = *(const v2f*)(w2b + ia.z);         \
    const v2f p3 = *(const v2f*)(w2b + ia.w);         \
    const v2f p4 = *(const v2f*)(w2b + ib.x);         \
    const v2f p5 = *(const v2f*)(w2b + ib.y);         \
    const v2f p6 = *(const v2f*)(w2b + ib.z);         \
    const v2f p7 = *(const v2f*)(w2b + ib.w);         \
    acc += p0; acc += p1; acc += p2; acc += p3;       \
    acc += p4; acc += p5; acc += p6; acc += p7;       \
  }

#define OUT_B8()                                      \
  {                                                   \
    const int4 ia = *(const int4*)(scr + k);          \
    const int4 ib = *(const int4*)(scr + k + 4);      \
    const float q0 = *(const float*)(wob + ia.x);     \
    const float q1 = *(const float*)(wob + ia.y);     \
    const float q2 = *(const float*)(wob + ia.z);     \
    const float q3 = *(const float*)(wob + ia.w);     \
    const float q4 = *(const float*)(wob + ib.x);     \
    const float q5 = *(const float*)(wob + ib.y);     \
    const float q6 = *(const float*)(wob + ib.z);     \
    const float q7 = *(const float*)(wob + ib.w);     \
    co += q0; co += q1; co += q2; co += q3;           \
    co += q4; co += q5; co += q6; co += q7;           \
  }

  for (int r = 0; r < 4; ++r) {
    const long b = (long)blockIdx.x * 64 + w * 4 + r;

    float c[4];
    if (cur1 != nullptr) {
#pragma unroll
      for (int i = 0; i < 4; ++i) c[i] = cur1[b * H1 + i * 64 + l];
    } else {
      const float* xr = x + b * IN_DIM;
#pragma unroll
      for (int i = 0; i < 4; ++i) {
        const int n = i * 64 + l;
        const float* wr = W1 + n * IN_DIM;
        float a = 0.f;
        for (int kk = 0; kk < IN_DIM; kk += 4) {
          const float4 wv = *(const float4*)(wr + kk);
          const float4 xv = *(const float4*)(xr + kk);
          a = fmaf(wv.x, xv.x, a);
          a = fmaf(wv.y, xv.y, a);
          a = fmaf(wv.z, xv.z, a);
          a = fmaf(wv.w, xv.w, a);
        }
        c[i] = a + b1[n];
      }
    }

    float m1[4] = {0.f, 0.f, 0.f, 0.f};
    float sp1[4] = {0.f, 0.f, 0.f, 0.f};
    float m2a = 0.f, m2b = 0.f, sp2a = 0.f, sp2b = 0.f;
    float mo = 0.f, spo = 0.f, cnt = 0.f;

    for (int t = 0; t < nsteps; ++t) {
      // ---- layer 1 LIF + spike masks ----
      float n0 = fmaf(0.5f, m1[0], c[0]) - sp1[0];
      float n1 = fmaf(0.5f, m1[1], c[1]) - sp1[1];
      float n2 = fmaf(0.5f, m1[2], c[2]) - sp1[2];
      float n3 = fmaf(0.5f, m1[3], c[3]) - sp1[3];
      const bool s0 = n0 > 1.0f;
      const bool s1 = n1 > 1.0f;
      const bool s2 = n2 > 1.0f;
      const bool s3 = n3 > 1.0f;
      m1[0] = n0; m1[1] = n1; m1[2] = n2; m1[3] = n3;
      sp1[0] = s0 ? 1.0f : 0.0f;
      sp1[1] = s1 ? 1.0f : 0.0f;
      sp1[2] = s2 ? 1.0f : 0.0f;
      sp1[3] = s3 ? 1.0f : 0.0f;
      const unsigned long long g0 = __ballot(s0);
      const unsigned long long g1 = __ballot(s1);
      const unsigned long long g2 = __ballot(s2);
      const unsigned long long g3 = __ballot(s3);
      const int pc0 = (int)__popcll(g0);
      const int pc1 = (int)__popcll(g1);
      const int pc2 = (int)__popcll(g2);
      const int pc3 = (int)__popcll(g3);
      const int S = pc0 + pc1 + pc2 + pc3;

      // ---- build spike-row offset list (rank-compacted, j-ascending) ----
      if (s0) scr[mbcnt64(g0)] = wr0;
      if (s1) scr[pc0 + mbcnt64(g1)] = wr1;
      if (s2) scr[pc0 + pc1 + mbcnt64(g2)] = wr2;
      if (s3) scr[pc0 + pc1 + pc2 + mbcnt64(g3)] = wr3;
      asm volatile("s_waitcnt lgkmcnt(0)" ::: "memory");

      // ---- cur2 = s1 @ W2^T (+ b2): exact-size clustered batches ----
      v2f acc = {0.f, 0.f};
      int k = 0;
      for (; k + 8 <= S; k += 8) MAIN_B8();
      if (S & 4) {
        const int4 ia = *(const int4*)(scr + k);
        const v2f p0 = *(const v2f*)(w2b + ia.x);
        const v2f p1 = *(const v2f*)(w2b + ia.y);
        const v2f p2 = *(const v2f*)(w2b + ia.z);
        const v2f p3 = *(const v2f*)(w2b + ia.w);
        acc += p0; acc += p1; acc += p2; acc += p3;
        k += 4;
      }
      if (S & 2) {
        const int2 ia = *(const int2*)(scr + k);
        const v2f p0 = *(const v2f*)(w2b + ia.x);
        const v2f p1 = *(const v2f*)(w2b + ia.y);
        acc += p0; acc += p1;
        k += 2;
      }
      if (S & 1) {
        const int i0 = scr[k];
        const v2f p0 = *(const v2f*)(w2b + i0);
        acc += p0;
      }
      const float a0 = acc.x + bb0;
      const float a1 = acc.y + bb1;

      // ---- layer 2 LIF ----
      m2a = fmaf(0.5f, m2a, a0) - sp2a;
      m2b = fmaf(0.5f, m2b, a1) - sp2b;
      const bool sa = m2a > 1.0f;
      const bool sb = m2b > 1.0f;
      const unsigned long long mA = __ballot(sa);
      const unsigned long long mB = __ballot(sb);
      sp2a = sa ? 1.0f : 0.0f;
      sp2b = sb ? 1.0f : 0.0f;
      const int pcA = (int)__popcll(mA);
      const int So = pcA + (int)__popcll(mB);

      // ---- output-layer offset list (evens ascending, then odds) ----
      if (sa) scr[mbcnt64(mA)] = or0;
      if (sb) scr[pcA + mbcnt64(mB)] = or1;
      asm volatile("s_waitcnt lgkmcnt(0)" ::: "memory");

      float co = 0.f;
      k = 0;
      for (; k + 8 <= So; k += 8) OUT_B8();
      if (So & 4) {
        const int4 ia = *(const int4*)(scr + k);
        const float q0 = *(const float*)(wob + ia.x);
        const float q1 = *(const float*)(wob + ia.y);
        const float q2 = *(const float*)(wob + ia.z);
        const float q3 = *(const float*)(wob + ia.w);
        co += q0; co += q1; co += q2; co += q3;
        k += 4;
      }
      if (So & 2) {
        const int2 ia = *(const int2*)(scr + k);
        const float q0 = *(const float*)(wob + ia.x);
        const float q1 = *(const float*)(wob + ia.y);
        co += q0; co += q1;
        k += 2;
      }
      if (So & 1) {
        const int i0 = scr[k];
        co += *(const float*)(wob + i0);
      }
      co += bol;

      // ---- output LIF + spike count ----
      mo = fmaf(0.5f, mo, co) - spo;
      const bool so = mo > 1.0f;
      spo = so ? 1.0f : 0.0f;
      cnt += spo;
    }

    if (l < NC) out[b * NC + l] = cnt;
  }
#undef MAIN_B8
#undef OUT_B8
}

// ---------------------------------------------------------------------------
extern "C" void kernel_launch(void* const* d_in, const int* in_sizes, int n_in,
                              void* d_out, int out_size, void* d_ws,
                              size_t ws_size, hipStream_t stream) {
  const float* x  = (const float*)d_in[0];
  const float* W1 = (const float*)d_in[1];
  const float* b1 = (const float*)d_in[2];
  const float* W2 = (const float*)d_in[3];
  const float* b2 = (const float*)d_in[4];
  const float* Wo = (const float*)d_in[5];
  const float* bo = (const float*)d_in[6];
  const int* nsp  = (const int*)d_in[7];
  float* outp = (float*)d_out;

  const size_t cur1_bytes = (size_t)B_TOT * H1 * sizeof(float);
  const size_t w2t_bytes  = (size_t)H1 * H2 * sizeof(float);
  const size_t wot_bytes  = (size_t)H2 * NC * sizeof(float);

  float* cur1 = nullptr;
  float* W2Tg = nullptr;
  float* WoTg = nullptr;

  if (ws_size >= cur1_bytes) {
    cur1 = (float*)d_ws;
    gemm1_kernel<<<B_TOT / 16, 256, 0, stream>>>(x, W1, b1, cur1);
  }
  if (ws_size >= cur1_bytes + w2t_bytes + wot_bytes) {
    W2Tg = (float*)((char*)d_ws + cur1_bytes);
    WoTg = W2Tg + H1 * H2;
    transpose_kernel<<<(H2 * H1 + NC * H2 + 1023) / 1024, 1024, 0, stream>>>(
        W2, Wo, W2Tg, WoTg);
  }

  hipFuncSetAttribute((const void*)snn_kernel,
                      hipFuncAttributeMaxDynamicSharedMemorySize, LDS_BYTES);
  snn_kernel<<<256, 1024, LDS_BYTES, stream>>>(cur1, W2Tg, WoTg, W2, Wo, x,
                                               W1, b1, b2, bo, nsp, outp);
}